// Round 6
// baseline (521.301 us; speedup 1.0000x reference)
//
#include <hip/hip_runtime.h>
#include <math.h>

// Problem constants
#define NN 100000
#define DD 128
#define EE 600000
#define RR 5
#define MCNT (RR * NN)          // 500000 sort buckets
#define NB1 489                 // ceil(MCNT / 1024)

#define WSTR 136                // padded slot stride (f16) for transposed W
#define HALF_SLOTS 192
#define SLAB 32                 // rows per GEMM slab; 100000 = 3125*32
#define NSLAB (NN / SLAB)

#define FILM_BLKS 256           // persistent film blocks in mixed dispatches
#define AGG_BLKS  6250          // NN/16 dst groups
#define SCAT_BLKS 2344          // ceil(EE/256)

typedef _Float16 v8h __attribute__((ext_vector_type(8)));
typedef _Float16 h4  __attribute__((ext_vector_type(4)));
typedef float    v4f __attribute__((ext_vector_type(4)));

__device__ __forceinline__ float gelu_exact(float v) {
    return 0.5f * v * (1.0f + erff(v * 0.7071067811865476f));
}

// ===========================================================================
// Device bodies (shared by combined dispatches)
// ===========================================================================

// film: xl = x@lins_w[r]; beta/gamma = x@films_w[r]+bias. W-stationary.
__device__ __forceinline__
void film_body(_Float16* Wl, _Float16* Al, int bid, int nblk,
               const _Float16* __restrict__ xh,
               const _Float16* __restrict__ Wt,
               const float* __restrict__ bias,
               _Float16* __restrict__ xl,
               _Float16* __restrict__ bh,
               _Float16* __restrict__ gh)
{
    const int tid  = threadIdx.x;
    const int wv   = tid >> 6;
    const int lane = tid & 63;
    const int l15  = lane & 15;
    const int quad = lane >> 4;

    for (int half = 0; half < 2; ++half) {
        __syncthreads();
        for (int u = tid; u < (HALF_SLOTS * WSTR) / 8; u += 256)
            *(v8h*)(Wl + (size_t)u * 8) =
                *(const v8h*)(Wt + (size_t)half * HALF_SLOTS * WSTR + (size_t)u * 8);

        const int c0 = half * 64 + wv * 16 + quad * 4;
        const float4 bb = *(const float4*)(bias + c0);
        const float4 bg = *(const float4*)(bias + DD + c0);

        for (int s = bid; s < NSLAB; s += nblk) {
            __syncthreads();
            #pragma unroll
            for (int j = 0; j < 2; ++j) {
                int u = tid + j * 256;
                int row = u >> 4, c8 = u & 15;
                *(v8h*)(Al + row * WSTR + c8 * 8) =
                    *(const v8h*)(xh + ((size_t)s * SLAB + row) * DD + c8 * 8);
            }
            __syncthreads();

            v4f acc[3][2];
            #pragma unroll
            for (int a = 0; a < 3; ++a)
                #pragma unroll
                for (int rt = 0; rt < 2; ++rt)
                    acc[a][rt] = (v4f){0.f, 0.f, 0.f, 0.f};

            #pragma unroll
            for (int ks = 0; ks < 4; ++ks) {
                v8h xf0 = *(v8h*)(Al + l15 * WSTR + ks * 32 + quad * 8);
                v8h xf1 = *(v8h*)(Al + (16 + l15) * WSTR + ks * 32 + quad * 8);
                v8h wf[3];
                #pragma unroll
                for (int a = 0; a < 3; ++a)
                    wf[a] = *(v8h*)(Wl + (a * 64 + wv * 16 + l15) * WSTR + ks * 32 + quad * 8);
                #pragma unroll
                for (int a = 0; a < 3; ++a) {
                    acc[a][0] = __builtin_amdgcn_mfma_f32_16x16x32_f16(wf[a], xf0, acc[a][0], 0, 0, 0);
                    acc[a][1] = __builtin_amdgcn_mfma_f32_16x16x32_f16(wf[a], xf1, acc[a][1], 0, 0, 0);
                }
            }

            #pragma unroll
            for (int rt = 0; rt < 2; ++rt) {
                const size_t row = (size_t)s * SLAB + rt * 16 + l15;
                v4f xv = acc[0][rt], bv = acc[1][rt], gv = acc[2][rt];
                h4 ox, ob, og;
                ox[0] = (_Float16)xv[0]; ox[1] = (_Float16)xv[1];
                ox[2] = (_Float16)xv[2]; ox[3] = (_Float16)xv[3];
                ob[0] = (_Float16)(bv[0] + bb.x); ob[1] = (_Float16)(bv[1] + bb.y);
                ob[2] = (_Float16)(bv[2] + bb.z); ob[3] = (_Float16)(bv[3] + bb.w);
                og[0] = (_Float16)(gv[0] + bg.x); og[1] = (_Float16)(gv[1] + bg.y);
                og[2] = (_Float16)(gv[2] + bg.z); og[3] = (_Float16)(gv[3] + bg.w);
                *(h4*)(xl + row * DD + c0) = ox;
                *(h4*)(bh + row * DD + c0) = ob;
                *(h4*)(gh + row * DD + c0) = og;
            }
        }
    }
}

// skip: oa = relu(gamma_s*(x@lin_skip)+beta_s), f16 out
__device__ __forceinline__
void skip_body(_Float16* Wl, _Float16* Al, int bid, int nblk,
               const _Float16* __restrict__ xh,
               const _Float16* __restrict__ Wt,
               _Float16* __restrict__ oa)
{
    const int tid  = threadIdx.x;
    const int wv   = tid >> 6;
    const int lane = tid & 63;
    const int l15  = lane & 15;
    const int quad = lane >> 4;

    for (int half = 0; half < 2; ++half) {
        __syncthreads();
        for (int u = tid; u < (HALF_SLOTS * WSTR) / 8; u += 256)
            *(v8h*)(Wl + (size_t)u * 8) =
                *(const v8h*)(Wt + (size_t)half * HALF_SLOTS * WSTR + (size_t)u * 8);

        const int c0 = half * 64 + wv * 16 + quad * 4;

        for (int s = bid; s < NSLAB; s += nblk) {
            __syncthreads();
            #pragma unroll
            for (int j = 0; j < 2; ++j) {
                int u = tid + j * 256;
                int row = u >> 4, c8 = u & 15;
                *(v8h*)(Al + row * WSTR + c8 * 8) =
                    *(const v8h*)(xh + ((size_t)s * SLAB + row) * DD + c8 * 8);
            }
            __syncthreads();

            v4f acc[3][2];
            #pragma unroll
            for (int a = 0; a < 3; ++a)
                #pragma unroll
                for (int rt = 0; rt < 2; ++rt)
                    acc[a][rt] = (v4f){0.f, 0.f, 0.f, 0.f};

            #pragma unroll
            for (int ks = 0; ks < 4; ++ks) {
                v8h xf0 = *(v8h*)(Al + l15 * WSTR + ks * 32 + quad * 8);
                v8h xf1 = *(v8h*)(Al + (16 + l15) * WSTR + ks * 32 + quad * 8);
                v8h wf[3];
                #pragma unroll
                for (int a = 0; a < 3; ++a)
                    wf[a] = *(v8h*)(Wl + (a * 64 + wv * 16 + l15) * WSTR + ks * 32 + quad * 8);
                #pragma unroll
                for (int a = 0; a < 3; ++a) {
                    acc[a][0] = __builtin_amdgcn_mfma_f32_16x16x32_f16(wf[a], xf0, acc[a][0], 0, 0, 0);
                    acc[a][1] = __builtin_amdgcn_mfma_f32_16x16x32_f16(wf[a], xf1, acc[a][1], 0, 0, 0);
                }
            }

            #pragma unroll
            for (int rt = 0; rt < 2; ++rt) {
                const size_t row = (size_t)s * SLAB + rt * 16 + l15;
                v4f xv = acc[0][rt], bv = acc[1][rt], gv = acc[2][rt];
                h4 o;
                o[0] = (_Float16)fmaxf(gv[0] * xv[0] + bv[0], 0.f);
                o[1] = (_Float16)fmaxf(gv[1] * xv[1] + bv[1], 0.f);
                o[2] = (_Float16)fmaxf(gv[2] * xv[2] + bv[2], 0.f);
                o[3] = (_Float16)fmaxf(gv[3] * xv[3] + bv[3], 0.f);
                *(h4*)(oa + row * DD + c0) = o;
            }
        }
    }
}

// agg: owner-computes, barrier-free, batched gathers, f16 oa RMW
__device__ __forceinline__
void agg_body(int abid, const int* __restrict__ rp, const int* __restrict__ srcs,
              const _Float16* __restrict__ xl, const _Float16* __restrict__ bh,
              const _Float16* __restrict__ gh, _Float16* __restrict__ oa)
{
    const int tid = threadIdx.x;
    const int d   = abid * 16 + (tid >> 4);
    const int c0  = (tid & 15) * 8;
    const int start = rp[d];
    const int end   = rp[d + 1];
    const int k = end - start;
    if (k <= 0) return;
    _Float16* dp = oa + (size_t)d * DD + c0;
    const v8h old = *(v8h*)dp;                     // prefetch RMW read
    const v8h gs = *(const v8h*)(gh + (size_t)d * DD + c0);
    const v8h bs = *(const v8h*)(bh + (size_t)d * DD + c0);

    float acc[8] = {0.f, 0.f, 0.f, 0.f, 0.f, 0.f, 0.f, 0.f};
    int p = start;
    while (p < end) {
        const int kb = min(end - p, 8);
        int sidx[8];
        #pragma unroll
        for (int j = 0; j < 8; ++j)
            sidx[j] = srcs[p + min(j, kb - 1)];    // clamped: always valid
        v8h xv[8];
        #pragma unroll
        for (int j = 0; j < 8; ++j)
            xv[j] = *(const v8h*)(xl + (size_t)sidx[j] * DD + c0);
        #pragma unroll
        for (int j = 0; j < 8; ++j) {
            if (j < kb) {
                #pragma unroll
                for (int q = 0; q < 8; ++q)
                    acc[q] += fmaxf((float)gs[q] * (float)xv[j][q] + (float)bs[q], 0.f);
            }
        }
        p += kb;
    }

    const float inv = 1.0f / (float)k;
    v8h nw;
    #pragma unroll
    for (int q = 0; q < 8; ++q)
        nw[q] = (_Float16)((float)old[q] + acc[q] * inv);
    *(v8h*)dp = nw;
}

// ===========================================================================
// Dispatch 1: prep (convert x, transpose weights) + edge count
// cnt must be zeroed beforehand (hipMemsetAsync).
// ===========================================================================
__global__ __launch_bounds__(256)
void prep_count(const float* __restrict__ x, _Float16* __restrict__ xh,
                const float* __restrict__ lin_skip_w,
                const float* __restrict__ film_skip_w,
                const float* __restrict__ lins_w,
                const float* __restrict__ films_w,
                const float* __restrict__ linear1_w,
                _Float16* __restrict__ wt,
                const int* __restrict__ ei, const int* __restrict__ et,
                int* __restrict__ cnt)
{
    const int b = blockIdx.x;
    if (b < 6250) {
        size_t u = (size_t)b * 256 + threadIdx.x;
        const float4 a = *(const float4*)(x + u * 8);
        const float4 c = *(const float4*)(x + u * 8 + 4);
        v8h o;
        o[0] = (_Float16)a.x; o[1] = (_Float16)a.y; o[2] = (_Float16)a.z; o[3] = (_Float16)a.w;
        o[4] = (_Float16)c.x; o[5] = (_Float16)c.y; o[6] = (_Float16)c.z; o[7] = (_Float16)c.w;
        *(v8h*)(xh + u * 8) = o;
    } else if (b < 6250 + 1216) {
        const int bb = (b - 6250) * 2 + (threadIdx.x >> 7);
        const int k  = threadIdx.x & 127;
        float v;
        _Float16* dst;
        if (bb < 6 * 384) {
            const int set = bb / 384;
            const int s   = bb % 384;
            const int half = s / 192;
            const int rem  = s % 192;
            const int a    = rem / 64;
            const int col  = half * 64 + (rem % 64);
            if (set == 0) {
                v = (a == 0) ? lin_skip_w[k * DD + col]
                             : film_skip_w[k * 2 * DD + (a - 1) * DD + col];
            } else {
                const int r = set - 1;
                v = (a == 0) ? lins_w[((size_t)r * DD + k) * DD + col]
                             : films_w[((size_t)r * DD + k) * 2 * DD + (a - 1) * DD + col];
            }
            dst = wt + (size_t)set * 384 * WSTR + (size_t)s * WSTR + k;
        } else {
            const int s = bb - 2304;
            v = linear1_w[k * DD + s];
            dst = wt + (size_t)2304 * WSTR + (size_t)s * WSTR + k;
        }
        *dst = (_Float16)v;
    } else {
        int e = (b - 6250 - 1216) * 256 + threadIdx.x;
        if (e < EE) atomicAdd(&cnt[(size_t)et[e] * NN + ei[EE + e]], 1);
    }
}

// ===========================================================================
// Scan kernels (counting-sort prefix)
// ===========================================================================
__global__ __launch_bounds__(256)
void scan1(const int* __restrict__ cnt, int* __restrict__ partial,
           int* __restrict__ bsum)
{
    __shared__ int s[256];
    const int t = threadIdx.x;
    const int base = blockIdx.x * 1024 + t * 4;
    int v[4], sum = 0;
    #pragma unroll
    for (int j = 0; j < 4; ++j) {
        v[j] = (base + j < MCNT) ? cnt[base + j] : 0;
        sum += v[j];
    }
    s[t] = sum;
    __syncthreads();
    for (int off = 1; off < 256; off <<= 1) {
        int x = (t >= off) ? s[t - off] : 0;
        __syncthreads();
        s[t] += x;
        __syncthreads();
    }
    int run = s[t] - sum;
    if (t == 255) bsum[blockIdx.x] = s[255];
    #pragma unroll
    for (int j = 0; j < 4; ++j) {
        if (base + j < MCNT) partial[base + j] = run;
        run += v[j];
    }
}

__global__ __launch_bounds__(512)
void scan2(const int* __restrict__ bsum, int* __restrict__ bsum2)
{
    __shared__ int s[512];
    const int t = threadIdx.x;
    const int v = (t < NB1) ? bsum[t] : 0;
    s[t] = v;
    __syncthreads();
    for (int off = 1; off < 512; off <<= 1) {
        int x = (t >= off) ? s[t - off] : 0;
        __syncthreads();
        s[t] += x;
        __syncthreads();
    }
    if (t < NB1) bsum2[t] = s[t] - v;
}

__global__ __launch_bounds__(256)
void scan3(const int* __restrict__ partial, const int* __restrict__ bsum2,
           int* __restrict__ rowptr, int* __restrict__ head)
{
    const int t = threadIdx.x;
    const int base = blockIdx.x * 1024 + t * 4;
    const int add = bsum2[blockIdx.x];
    #pragma unroll
    for (int j = 0; j < 4; ++j) {
        if (base + j < MCNT) {
            int v = partial[base + j] + add;
            rowptr[base + j] = v;
            head[base + j]   = v;
        }
    }
    if (blockIdx.x == 0 && t == 0) rowptr[MCNT] = EE;
}

// ===========================================================================
// Dispatch D0: film_0 (blocks 0..255) + skip (256..511) + scatter (512..2855)
// ===========================================================================
__global__ __launch_bounds__(256)
void d0_kernel(const _Float16* __restrict__ xh, const _Float16* __restrict__ wt,
               const float* __restrict__ films_b,
               _Float16* __restrict__ xl0, _Float16* __restrict__ bh0,
               _Float16* __restrict__ gh0, _Float16* __restrict__ oa,
               const int* __restrict__ ei, const int* __restrict__ et,
               int* __restrict__ head, int* __restrict__ srcs)
{
    __shared__ _Float16 Wl[HALF_SLOTS * WSTR];
    __shared__ _Float16 Al[SLAB * WSTR];
    const int b = blockIdx.x;
    if (b < FILM_BLKS) {
        film_body(Wl, Al, b, FILM_BLKS, xh, wt + (size_t)384 * WSTR, films_b,
                  xl0, bh0, gh0);
    } else if (b < 2 * FILM_BLKS) {
        skip_body(Wl, Al, b - FILM_BLKS, FILM_BLKS, xh, wt, oa);
    } else {
        int e = (b - 2 * FILM_BLKS) * 256 + threadIdx.x;
        if (e < EE) {
            int pos = atomicAdd(&head[(size_t)et[e] * NN + ei[EE + e]], 1);
            srcs[pos] = ei[e];
        }
    }
}

// ===========================================================================
// Pair dispatch: film_{r+1} (blocks 0..255) + agg_r (blocks 256..6505)
// ===========================================================================
__global__ __launch_bounds__(256)
void pair_kernel(const _Float16* __restrict__ xh,
                 const _Float16* __restrict__ Wt_next,
                 const float* __restrict__ bias_next,
                 _Float16* __restrict__ xl_w, _Float16* __restrict__ bh_w,
                 _Float16* __restrict__ gh_w,
                 const int* __restrict__ rp, const int* __restrict__ srcs,
                 const _Float16* __restrict__ xl_r, const _Float16* __restrict__ bh_r,
                 const _Float16* __restrict__ gh_r, _Float16* __restrict__ oa)
{
    __shared__ _Float16 Wl[HALF_SLOTS * WSTR];
    __shared__ _Float16 Al[SLAB * WSTR];
    const int b = blockIdx.x;
    if (b < FILM_BLKS) {
        film_body(Wl, Al, b, FILM_BLKS, xh, Wt_next, bias_next, xl_w, bh_w, gh_w);
    } else {
        agg_body(b - FILM_BLKS, rp, srcs, xl_r, bh_r, gh_r, oa);
    }
}

// standalone agg (last relation; no LDS -> full occupancy)
__global__ __launch_bounds__(256)
void agg_kernel(const int* __restrict__ rp, const int* __restrict__ srcs,
                const _Float16* __restrict__ xl, const _Float16* __restrict__ bh,
                const _Float16* __restrict__ gh, _Float16* __restrict__ oa)
{
    agg_body(blockIdx.x, rp, srcs, xl, bh, gh, oa);
}

// ===========================================================================
// final: out = gelu(oa) @ linear1_w + linear1_b  (f16 in, fp32 out)
// ===========================================================================
__global__ __launch_bounds__(256)
void final_mfma(const _Float16* __restrict__ oa,
                const _Float16* __restrict__ Wt,
                const float* __restrict__ bias,
                float* __restrict__ out)
{
    __shared__ _Float16 Wl[DD * WSTR];
    __shared__ _Float16 Al[SLAB * WSTR];
    const int tid  = threadIdx.x;
    const int wv   = tid >> 6;
    const int lane = tid & 63;
    const int l15  = lane & 15;
    const int quad = lane >> 4;

    for (int u = tid; u < (DD * WSTR) / 8; u += 256)
        *(v8h*)(Wl + (size_t)u * 8) = *(const v8h*)(Wt + (size_t)u * 8);

    float4 bf[2];
    #pragma unroll
    for (int ct = 0; ct < 2; ++ct)
        bf[ct] = *(const float4*)(bias + wv * 32 + ct * 16 + quad * 4);

    for (int s = blockIdx.x; s < NSLAB; s += gridDim.x) {
        __syncthreads();
        #pragma unroll
        for (int j = 0; j < 2; ++j) {
            int u = tid + j * 256;
            int row = u >> 4, c8 = (u & 15) * 8;
            v8h g = *(const v8h*)(oa + ((size_t)s * SLAB + row) * DD + c8);
            v8h o;
            #pragma unroll
            for (int q = 0; q < 8; ++q)
                o[q] = (_Float16)gelu_exact((float)g[q]);
            *(v8h*)(Al + row * WSTR + c8) = o;
        }
        __syncthreads();

        v4f acc[2][2];
        #pragma unroll
        for (int ct = 0; ct < 2; ++ct)
            #pragma unroll
            for (int rt = 0; rt < 2; ++rt)
                acc[ct][rt] = (v4f){0.f, 0.f, 0.f, 0.f};

        #pragma unroll
        for (int ks = 0; ks < 4; ++ks) {
            v8h xf0 = *(v8h*)(Al + l15 * WSTR + ks * 32 + quad * 8);
            v8h xf1 = *(v8h*)(Al + (16 + l15) * WSTR + ks * 32 + quad * 8);
            v8h wf[2];
            #pragma unroll
            for (int ct = 0; ct < 2; ++ct)
                wf[ct] = *(v8h*)(Wl + (wv * 32 + ct * 16 + l15) * WSTR + ks * 32 + quad * 8);
            #pragma unroll
            for (int ct = 0; ct < 2; ++ct) {
                acc[ct][0] = __builtin_amdgcn_mfma_f32_16x16x32_f16(wf[ct], xf0, acc[ct][0], 0, 0, 0);
                acc[ct][1] = __builtin_amdgcn_mfma_f32_16x16x32_f16(wf[ct], xf1, acc[ct][1], 0, 0, 0);
            }
        }

        #pragma unroll
        for (int ct = 0; ct < 2; ++ct)
            #pragma unroll
            for (int rt = 0; rt < 2; ++rt) {
                const size_t row = (size_t)s * SLAB + rt * 16 + l15;
                const int c0 = wv * 32 + ct * 16 + quad * 4;
                float4 o;
                o.x = acc[ct][rt][0] + bf[ct].x;
                o.y = acc[ct][rt][1] + bf[ct].y;
                o.z = acc[ct][rt][2] + bf[ct].z;
                o.w = acc[ct][rt][3] + bf[ct].w;
                *(float4*)(out + row * DD + c0) = o;
            }
    }
}

extern "C" void kernel_launch(void* const* d_in, const int* in_sizes, int n_in,
                              void* d_out, int out_size, void* d_ws, size_t ws_size,
                              hipStream_t stream)
{
    const float* x           = (const float*)d_in[0];
    const int*   ei          = (const int*)d_in[1];
    const int*   et          = (const int*)d_in[2];
    const float* lin_skip_w  = (const float*)d_in[3];
    const float* film_skip_w = (const float*)d_in[4];
    const float* lins_w      = (const float*)d_in[5];
    const float* films_w     = (const float*)d_in[6];
    const float* films_b     = (const float*)d_in[7];
    const float* linear1_w   = (const float*)d_in[8];
    const float* linear1_b   = (const float*)d_in[9];
    float* out = (float*)d_out;
    char*  ws  = (char*)d_ws;

    // workspace layout (bytes, 256-aligned) — ~206 MB total
    _Float16* xh      = (_Float16*)(ws);                   // 25,600,000
    _Float16* wt      = (_Float16*)(ws + 25600000);        //    661,504
    _Float16* xl0     = (_Float16*)(ws + 26261504);        // 25,600,000
    _Float16* bh0     = (_Float16*)(ws + 51861504);        // 25,600,000
    _Float16* gh0     = (_Float16*)(ws + 77461504);        // 25,600,000
    _Float16* xl1     = (_Float16*)(ws + 103061504);       // 25,600,000
    _Float16* bh1     = (_Float16*)(ws + 128661504);       // 25,600,000
    _Float16* gh1     = (_Float16*)(ws + 154261504);       // 25,600,000
    _Float16* oa      = (_Float16*)(ws + 179861504);       // 25,600,000
    int*      cnt     = (int*)     (ws + 205461504);       //  2,000,000
    int*      partial = (int*)     (ws + 207461504);       //  2,000,000
    int*      rowptr  = (int*)     (ws + 209461504);       //  2,000,128
    int*      head    = (int*)     (ws + 211461632);       //  2,000,000
    int*      srcs    = (int*)     (ws + 213461632);       //  2,400,000
    int*      bsum    = (int*)     (ws + 215861632);       //      4,096
    int*      bsum2   = (int*)     (ws + 215865728);       //      4,096

    _Float16* xlb[2] = {xl0, xl1};
    _Float16* bhb[2] = {bh0, bh1};
    _Float16* ghb[2] = {gh0, gh1};

    hipMemsetAsync(cnt, 0, (size_t)MCNT * sizeof(int), stream);
    prep_count<<<6250 + 1216 + SCAT_BLKS, 256, 0, stream>>>(
        x, xh, lin_skip_w, film_skip_w, lins_w, films_w, linear1_w, wt,
        ei, et, cnt);
    scan1<<<NB1, 256, 0, stream>>>(cnt, partial, bsum);
    scan2<<<1, 512, 0, stream>>>(bsum, bsum2);
    scan3<<<NB1, 256, 0, stream>>>(partial, bsum2, rowptr, head);

    // D0: film_0 + skip + scatter
    d0_kernel<<<2 * FILM_BLKS + SCAT_BLKS, 256, 0, stream>>>(
        xh, wt, films_b, xl0, bh0, gh0, oa, ei, et, head, srcs);

    // D1..D4: agg_r + film_{r+1}
    for (int r = 0; r < RR - 1; ++r) {
        pair_kernel<<<FILM_BLKS + AGG_BLKS, 256, 0, stream>>>(
            xh, wt + (size_t)(r + 2) * 384 * WSTR,
            films_b + (size_t)(r + 1) * 2 * DD,
            xlb[(r + 1) & 1], bhb[(r + 1) & 1], ghb[(r + 1) & 1],
            rowptr + (size_t)r * NN, srcs,
            xlb[r & 1], bhb[r & 1], ghb[r & 1], oa);
    }

    // D5: agg_4 (relation 4 uses buffer set 0)
    agg_kernel<<<AGG_BLKS, 256, 0, stream>>>(
        rowptr + (size_t)4 * NN, srcs, xlb[0], bhb[0], ghb[0], oa);

    // D6: final
    final_mfma<<<512, 256, 0, stream>>>(oa, wt + (size_t)2304 * WSTR,
                                        linear1_b, out);
}